// Round 1
// baseline (388.320 us; speedup 1.0000x reference)
//
#include <hip/hip_runtime.h>
#include <hip/hip_bf16.h>
#include <cstdint>

typedef __bf16 bf16;
typedef bf16 bf16x4 __attribute__((ext_vector_type(4)));
typedef bf16 bf16x8 __attribute__((ext_vector_type(8)));
typedef float f32x4 __attribute__((ext_vector_type(4)));

#define B_  2048
#define E_  512
#define H_  512
#define V_  50257
#define K1_ 1024

__device__ __forceinline__ void gload_lds16(const void* g, void* l) {
  __builtin_amdgcn_global_load_lds(
      (const __attribute__((address_space(1))) void*)g,
      (__attribute__((address_space(3))) void*)l, 16, 0, 0);
}

__device__ __forceinline__ float wave_sum(float v) {
#pragma unroll
  for (int o = 32; o > 0; o >>= 1) v += __shfl_xor(v, o, 64);
  return v;
}

// ---------------------------------------------------------------------------
// prep: gru_in bf16 [2048][1024] = [h_prev | x];  wzrh bf16 [1536][1024]
// ---------------------------------------------------------------------------
__global__ __launch_bounds__(256) void prep_kernel(
    const float* __restrict__ hprev, const float* __restrict__ x,
    const float* __restrict__ Wz, const float* __restrict__ Wr,
    const float* __restrict__ Wh,
    bf16* __restrict__ gin, bf16* __restrict__ wzrh)
{
  const int i = blockIdx.x * 256 + threadIdx.x;  // one float4 chunk each
  constexpr int N1 = B_ * K1_ / 4;   // 524288
  constexpr int N2 = 1536 * K1_ / 4; // 393216
  if (i < N1) {
    int e = i * 4;
    int m = e >> 10, k = e & 1023;
    const float* src = (k < 512) ? (hprev + (size_t)m * 512 + k)
                                 : (x + (size_t)m * 512 + (k - 512));
    f32x4 v = *reinterpret_cast<const f32x4*>(src);
    bf16x4 t; t[0]=(bf16)v[0]; t[1]=(bf16)v[1]; t[2]=(bf16)v[2]; t[3]=(bf16)v[3];
    *reinterpret_cast<bf16x4*>(gin + e) = t;
  } else if (i < N1 + N2) {
    int e = (i - N1) * 4;
    int which = e >> 19;          // 512*1024 = 2^19
    int off = e & ((1 << 19) - 1);
    const float* W = (which == 0) ? Wz : (which == 1) ? Wr : Wh;
    f32x4 v = *reinterpret_cast<const f32x4*>(W + off);
    bf16x4 t; t[0]=(bf16)v[0]; t[1]=(bf16)v[1]; t[2]=(bf16)v[2]; t[3]=(bf16)v[3];
    *reinterpret_cast<bf16x4*>(wzrh + e) = t;
  }
}

// ---------------------------------------------------------------------------
// generic bf16 GEMM: C[M][N] = A[M][K] @ Bm[N][K]^T  (fp32 out)
// BM=BN=128, BK=64, 256 threads, 2x2 waves of 4x4 16x16x32 MFMAs
// M%128==0, N%128==0, K%64==0
// ---------------------------------------------------------------------------
__global__ __launch_bounds__(256) void gemm_bf16_nt(
    const bf16* __restrict__ A, const bf16* __restrict__ Bm,
    float* __restrict__ C, int M, int N, int K)
{
  __shared__ bf16 As[128 * 64];
  __shared__ bf16 Bs[128 * 64];
  const int tid = threadIdx.x;
  const int wid = tid >> 6, lane = tid & 63;
  const int bm = blockIdx.x, bn = blockIdx.y;
  const int wm = (wid >> 1) * 64, wn = (wid & 1) * 64;
  f32x4 acc[4][4] = {};
  const size_t a_row0 = (size_t)bm * 128;
  const size_t b_row0 = (size_t)bn * 128;

  for (int k0 = 0; k0 < K; k0 += 64) {
#pragma unroll
    for (int i = 0; i < 4; ++i) {
      int base = i * 256 + wid * 64;      // wave-uniform chunk base
      int idx = base + lane;
      int row = idx >> 3;
      int col = (idx & 7) << 3;
      gload_lds16(A + (a_row0 + row) * K + (k0 + col), &As[base * 8]);
      gload_lds16(Bm + (b_row0 + row) * K + (k0 + col), &Bs[base * 8]);
    }
    asm volatile("s_waitcnt vmcnt(0)" ::: "memory");
    __syncthreads();
#pragma unroll
    for (int kk = 0; kk < 2; ++kk) {
      bf16x8 af[4], bb[4];
#pragma unroll
      for (int i = 0; i < 4; ++i)
        af[i] = *reinterpret_cast<const bf16x8*>(
            &As[(wm + i * 16 + (lane & 15)) * 64 + kk * 32 + (lane >> 4) * 8]);
#pragma unroll
      for (int j = 0; j < 4; ++j)
        bb[j] = *reinterpret_cast<const bf16x8*>(
            &Bs[(wn + j * 16 + (lane & 15)) * 64 + kk * 32 + (lane >> 4) * 8]);
#pragma unroll
      for (int i = 0; i < 4; ++i)
#pragma unroll
        for (int j = 0; j < 4; ++j)
          acc[i][j] = __builtin_amdgcn_mfma_f32_16x16x32_bf16(af[i], bb[j], acc[i][j], 0, 0, 0);
    }
    __syncthreads();
  }

  const int r0 = (lane >> 4) * 4, cc = lane & 15;
#pragma unroll
  for (int i = 0; i < 4; ++i)
#pragma unroll
    for (int j = 0; j < 4; ++j) {
      int n = bn * 128 + wn + j * 16 + cc;
#pragma unroll
      for (int q = 0; q < 4; ++q) {
        int mm = bm * 128 + wm + i * 16 + r0 + q;
        C[(size_t)mm * N + n] = acc[i][j][q];
      }
    }
}

// ---------------------------------------------------------------------------
// LN(+bias) + sigmoid for z and r; emit z (fp32) and cand_in bf16 [h_prev*r|x]
// one block per batch row
// ---------------------------------------------------------------------------
__global__ __launch_bounds__(256) void ln_zr_kernel(
    const float* __restrict__ zrp,
    const float* __restrict__ bz, const float* __restrict__ br,
    const float* __restrict__ gz, const float* __restrict__ bez,
    const float* __restrict__ gr, const float* __restrict__ ber,
    const float* __restrict__ hprev, const float* __restrict__ x,
    float* __restrict__ zbuf, bf16* __restrict__ cand)
{
  const int m = blockIdx.x, tid = threadIdx.x;
  const int wid = tid >> 6, lane = tid & 63;
  float zv[2], rv[2];
  float s0 = 0, s1 = 0, s2 = 0, s3 = 0;
#pragma unroll
  for (int e = 0; e < 2; ++e) {
    int n = tid + e * 256;
    float a = zrp[(size_t)m * 1024 + n] + bz[n];
    float b = zrp[(size_t)m * 1024 + 512 + n] + br[n];
    zv[e] = a; rv[e] = b;
    s0 += a; s1 += a * a; s2 += b; s3 += b * b;
  }
  s0 = wave_sum(s0); s1 = wave_sum(s1); s2 = wave_sum(s2); s3 = wave_sum(s3);
  __shared__ float red[4][4];
  if (lane == 0) { red[wid][0] = s0; red[wid][1] = s1; red[wid][2] = s2; red[wid][3] = s3; }
  __syncthreads();
  float zs = red[0][0] + red[1][0] + red[2][0] + red[3][0];
  float zq = red[0][1] + red[1][1] + red[2][1] + red[3][1];
  float rs = red[0][2] + red[1][2] + red[2][2] + red[3][2];
  float rq = red[0][3] + red[1][3] + red[2][3] + red[3][3];
  float zm = zs * (1.f / 512.f), zvr = zq * (1.f / 512.f) - zm * zm;
  float rm = rs * (1.f / 512.f), rvr = rq * (1.f / 512.f) - rm * rm;
  float zrs_ = rsqrtf(zvr + 1e-5f), rrs = rsqrtf(rvr + 1e-5f);
#pragma unroll
  for (int e = 0; e < 2; ++e) {
    int n = tid + e * 256;
    float zval = 1.f / (1.f + expf(-((zv[e] - zm) * zrs_ * gz[n] + bez[n])));
    float rval = 1.f / (1.f + expf(-((rv[e] - rm) * rrs * gr[n] + ber[n])));
    zbuf[(size_t)m * 512 + n] = zval;
    cand[(size_t)m * 1024 + n] = (bf16)(hprev[(size_t)m * 512 + n] * rval);
    cand[(size_t)m * 1024 + 512 + n] = (bf16)(x[(size_t)m * 512 + n]);
  }
}

// ---------------------------------------------------------------------------
// LN(+bias) + tanh for h_new; h_t = (1-z)*h_prev + z*h_new
// ---------------------------------------------------------------------------
__global__ __launch_bounds__(256) void ln_h_kernel(
    const float* __restrict__ hpre, const float* __restrict__ bh,
    const float* __restrict__ gh, const float* __restrict__ beh,
    const float* __restrict__ zbuf, const float* __restrict__ hprev,
    float* __restrict__ outh, bf16* __restrict__ htb)
{
  const int m = blockIdx.x, tid = threadIdx.x;
  const int wid = tid >> 6, lane = tid & 63;
  float v[2];
  float s0 = 0, s1 = 0;
#pragma unroll
  for (int e = 0; e < 2; ++e) {
    int n = tid + e * 256;
    float a = hpre[(size_t)m * 512 + n] + bh[n];
    v[e] = a; s0 += a; s1 += a * a;
  }
  s0 = wave_sum(s0); s1 = wave_sum(s1);
  __shared__ float red[4][2];
  if (lane == 0) { red[wid][0] = s0; red[wid][1] = s1; }
  __syncthreads();
  float ss = red[0][0] + red[1][0] + red[2][0] + red[3][0];
  float sq = red[0][1] + red[1][1] + red[2][1] + red[3][1];
  float mean = ss * (1.f / 512.f), var = sq * (1.f / 512.f) - mean * mean;
  float rstd = rsqrtf(var + 1e-5f);
#pragma unroll
  for (int e = 0; e < 2; ++e) {
    int n = tid + e * 256;
    float hn = tanhf((v[e] - mean) * rstd * gh[n] + beh[n]);
    float z = zbuf[(size_t)m * 512 + n];
    float ht = (1.f - z) * hprev[(size_t)m * 512 + n] + z * hn;
    outh[(size_t)m * 512 + n] = ht;
    htb[(size_t)m * 512 + n] = (bf16)ht;
  }
}

// ---------------------------------------------------------------------------
// big GEMM: Y[2048][V] = A[2048][512](bf16) @ Wo[V][512](fp32->bf16)^T + bo
// ---------------------------------------------------------------------------
__global__ __launch_bounds__(256) void gemm_out_kernel(
    const bf16* __restrict__ A, const float* __restrict__ Wo,
    const float* __restrict__ bo, float* __restrict__ Y)
{
  __shared__ bf16 As[128 * 64];
  __shared__ bf16 Bs[128 * 64];
  constexpr int K = 512;
  const int tid = threadIdx.x;
  const int wid = tid >> 6, lane = tid & 63;
  const int bm = blockIdx.x, bn = blockIdx.y;
  const int wm = (wid >> 1) * 64, wn = (wid & 1) * 64;
  f32x4 acc[4][4] = {};

  for (int k0 = 0; k0 < K; k0 += 64) {
#pragma unroll
    for (int i = 0; i < 4; ++i) {
      int base = i * 256 + wid * 64;
      int idx = base + lane;
      int row = idx >> 3, col = (idx & 7) << 3;
      gload_lds16(A + ((size_t)bm * 128 + row) * K + (k0 + col), &As[base * 8]);
    }
    // stage Wo fp32 -> bf16 into Bs
#pragma unroll
    for (int i = 0; i < 8; ++i) {
      int idx = i * 256 + tid;
      int row = idx >> 4;           // 16 float4 per 64-wide row
      int c4 = (idx & 15) * 4;
      int n = bn * 128 + row;
      int nc = (n < V_) ? n : (V_ - 1);
      f32x4 v = *reinterpret_cast<const f32x4*>(Wo + (size_t)nc * K + k0 + c4);
      bf16x4 t; t[0]=(bf16)v[0]; t[1]=(bf16)v[1]; t[2]=(bf16)v[2]; t[3]=(bf16)v[3];
      *reinterpret_cast<bf16x4*>(&Bs[row * 64 + c4]) = t;
    }
    asm volatile("s_waitcnt vmcnt(0)" ::: "memory");
    __syncthreads();
#pragma unroll
    for (int kk = 0; kk < 2; ++kk) {
      bf16x8 af[4], bb[4];
#pragma unroll
      for (int i = 0; i < 4; ++i)
        af[i] = *reinterpret_cast<const bf16x8*>(
            &As[(wm + i * 16 + (lane & 15)) * 64 + kk * 32 + (lane >> 4) * 8]);
#pragma unroll
      for (int j = 0; j < 4; ++j)
        bb[j] = *reinterpret_cast<const bf16x8*>(
            &Bs[(wn + j * 16 + (lane & 15)) * 64 + kk * 32 + (lane >> 4) * 8]);
#pragma unroll
      for (int i = 0; i < 4; ++i)
#pragma unroll
        for (int j = 0; j < 4; ++j)
          acc[i][j] = __builtin_amdgcn_mfma_f32_16x16x32_bf16(af[i], bb[j], acc[i][j], 0, 0, 0);
    }
    __syncthreads();
  }

  const int r0 = (lane >> 4) * 4, cc = lane & 15;
#pragma unroll
  for (int i = 0; i < 4; ++i)
#pragma unroll
    for (int j = 0; j < 4; ++j) {
      int n = bn * 128 + wn + j * 16 + cc;
      if (n < V_) {
        float bia = bo[n];
#pragma unroll
        for (int q = 0; q < 4; ++q) {
          int mm = bm * 128 + wm + i * 16 + r0 + q;
          Y[(size_t)mm * V_ + n] = acc[i][j][q] + bia;
        }
      }
    }
}

// ---------------------------------------------------------------------------
extern "C" void kernel_launch(void* const* d_in, const int* in_sizes, int n_in,
                              void* d_out, int out_size, void* d_ws, size_t ws_size,
                              hipStream_t stream) {
  const float* x     = (const float*)d_in[0];
  const float* hprev = (const float*)d_in[1];
  const float* Wz    = (const float*)d_in[2];
  const float* bz    = (const float*)d_in[3];
  const float* gz    = (const float*)d_in[4];
  const float* bez   = (const float*)d_in[5];
  const float* Wr    = (const float*)d_in[6];
  const float* br    = (const float*)d_in[7];
  const float* gr    = (const float*)d_in[8];
  const float* ber   = (const float*)d_in[9];
  const float* Wh    = (const float*)d_in[10];
  const float* bh    = (const float*)d_in[11];
  const float* gh    = (const float*)d_in[12];
  const float* beh   = (const float*)d_in[13];
  const float* Wo    = (const float*)d_in[14];
  const float* bo    = (const float*)d_in[15];

  float* out_h = (float*)d_out;
  float* out_y = out_h + (size_t)B_ * H_;

  char* ws = (char*)d_ws;
  bf16*  gin  = (bf16*)(ws);                      // 4 MB   [2048][1024]
  bf16*  wzrh = (bf16*)(ws + ((size_t)4 << 20));  // 3 MB   [1536][1024]
  float* zrp  = (float*)(ws + ((size_t)7 << 20)); // 8 MB   [2048][1024]
  float* zbuf = (float*)(ws + ((size_t)15 << 20));// 4 MB   [2048][512]
  bf16*  cand = (bf16*)(ws + ((size_t)19 << 20)); // 4 MB   [2048][1024]
  float* hpre = (float*)(ws + ((size_t)23 << 20));// 4 MB   [2048][512]
  bf16*  htb  = (bf16*)(ws + ((size_t)27 << 20)); // 2 MB   [2048][512]

  prep_kernel<<<3584, 256, 0, stream>>>(hprev, x, Wz, Wr, Wh, gin, wzrh);
  gemm_bf16_nt<<<dim3(16, 8), 256, 0, stream>>>(gin, wzrh, zrp, B_, 1024, K1_);
  ln_zr_kernel<<<B_, 256, 0, stream>>>(zrp, bz, br, gz, bez, gr, ber, hprev, x, zbuf, cand);
  gemm_bf16_nt<<<dim3(16, 4), 256, 0, stream>>>(cand, wzrh + (size_t)1024 * 1024, hpre, B_, 512, K1_);
  ln_h_kernel<<<B_, 256, 0, stream>>>(hpre, bh, gh, beh, zbuf, hprev, out_h, htb);
  gemm_out_kernel<<<dim3(16, 393), 256, 0, stream>>>(htb, Wo, bo, out_y);
}